// Round 1
// baseline (158.423 us; speedup 1.0000x reference)
//
#include <hip/hip_runtime.h>

// SDT forward, fused single kernel.
// Identity used: out[b,o] = sum_l P[b,l] * value[l,o], where
//   P[b,l] = prod_{d=0..7} max(branch_prob, 1e-5), branch from leaf bits.
// reg = sum_{b,node} (-0.5*2^-depth/8192) * log(max(p*(1-p),1e-5)).

constexpr int Bsz = 8192, D = 512, NN = 255, LV = 256, O = 64;
constexpr int B_ROWS = 16;   // rows per block
constexpr int KC = 64;       // K chunk

// LDS layout (floats):
//  phase 1: Ws_lds[64][256] at 0 (16384), xsT[64][18] at 16384 (1152)
//  phase 2: L/p [16][257] at 0, P [16][257] at 4112, red[4] at 8224
__global__ __launch_bounds__(256, 2) void sdt_fused(
    const float* __restrict__ x, const float* __restrict__ Ws,
    const float* __restrict__ bs, const float* __restrict__ value,
    float* __restrict__ out, float* __restrict__ reg_out)
{
  __shared__ float smem[16384 + KC * 18];
  float* Ws_lds = smem;            // [KC][256]
  float* xsT    = smem + 16384;    // [KC][18]
  float* L_lds  = smem;            // [16][257] (logits, then p in-place)
  float* P_lds  = smem + 16 * 257; // [16][257]
  float* red    = smem + 32 * 257; // [4]

  const int t  = threadIdx.x;
  const int cg = t & 31;   // cols cg*8 .. cg*8+7
  const int rg = t >> 5;   // rows rg*2, rg*2+1
  const int R0 = blockIdx.x * B_ROWS;

  float acc[2][8];
#pragma unroll
  for (int i = 0; i < 2; i++)
#pragma unroll
    for (int j = 0; j < 8; j++) acc[i][j] = 0.f;

  // ---------------- Phase 1: logits = x @ Ws ----------------
  for (int k0 = 0; k0 < D; k0 += KC) {
    __syncthreads();
    // stage Ws chunk [KC][255] -> padded [KC][256]
    {
      const float4* wsrc = (const float4*)(Ws + k0 * NN);
      for (int idx4 = t; idx4 < (KC * NN) / 4; idx4 += 256) {
        float4 v4 = wsrc[idx4];
        int e = idx4 * 4;
#pragma unroll
        for (int j = 0; j < 4; j++) {
          int elem = e + j;
          int k = elem / 255;              // magic-mul, compile-time const
          Ws_lds[elem + k] = ((const float*)&v4)[j];  // k*256 + (elem-k*255)
        }
      }
    }
    // stage x chunk transposed: xsT[k][row], row-pad 18 for alignment
    {
      int r = t >> 4, kq = (t & 15) * 4;
      float4 xv = *(const float4*)(x + (R0 + r) * D + k0 + kq);
      xsT[(kq + 0) * 18 + r] = xv.x;
      xsT[(kq + 1) * 18 + r] = xv.y;
      xsT[(kq + 2) * 18 + r] = xv.z;
      xsT[(kq + 3) * 18 + r] = xv.w;
    }
    __syncthreads();
#pragma unroll 4
    for (int kk = 0; kk < KC; kk++) {
      float2 xv = *(const float2*)&xsT[kk * 18 + rg * 2];
      float4 w0 = *(const float4*)&Ws_lds[kk * 256 + cg * 8];
      float4 w1 = *(const float4*)&Ws_lds[kk * 256 + cg * 8 + 4];
      acc[0][0] += xv.x * w0.x; acc[0][1] += xv.x * w0.y;
      acc[0][2] += xv.x * w0.z; acc[0][3] += xv.x * w0.w;
      acc[0][4] += xv.x * w1.x; acc[0][5] += xv.x * w1.y;
      acc[0][6] += xv.x * w1.z; acc[0][7] += xv.x * w1.w;
      acc[1][0] += xv.y * w0.x; acc[1][1] += xv.y * w0.y;
      acc[1][2] += xv.y * w0.z; acc[1][3] += xv.y * w0.w;
      acc[1][4] += xv.y * w1.x; acc[1][5] += xv.y * w1.y;
      acc[1][6] += xv.y * w1.z; acc[1][7] += xv.y * w1.w;
    }
  }
  __syncthreads();  // all Ws_lds reads done before overwrite

  // write logits (+bias) to L_lds[16][257]
  {
    float bias[8];
#pragma unroll
    for (int j = 0; j < 8; j++) {
      int c = cg * 8 + j;
      bias[j] = (c < NN) ? bs[c] : 0.f;
    }
#pragma unroll
    for (int r2 = 0; r2 < 2; r2++) {
      int row = rg * 2 + r2;
#pragma unroll
      for (int j = 0; j < 8; j++)
        L_lds[row * 257 + cg * 8 + j] = acc[r2][j] + bias[j];
    }
  }
  __syncthreads();

  // ---------------- Phase 2a: p = sigmoid, reg partials ----------------
  float regsum = 0.f;
  if (t < NN) {
    for (int r = 0; r < B_ROWS; r++) {
      float Lv = L_lds[r * 257 + t];
      float p = 1.f / (1.f + __expf(-Lv));
      L_lds[r * 257 + t] = p;  // in-place: this thread owns column t
      regsum += __logf(fmaxf(p * (1.f - p), 1e-5f));
    }
    int d = 31 - __clz(t + 1);
    regsum *= -0.5f / (8192.0f * (float)(1 << d));
  }
#pragma unroll
  for (int off = 32; off; off >>= 1) regsum += __shfl_down(regsum, off, 64);
  if ((t & 63) == 0) red[t >> 6] = regsum;
  __syncthreads();  // p visible + red visible

  // ---------------- Phase 2b: path products P[r][leaf] ----------------
  for (int r = 0; r < B_ROWS; r++) {
    float P = 1.f;
#pragma unroll
    for (int d = 0; d < 8; d++) {
      int node = (1 << d) - 1 + (t >> (8 - d));
      float p = L_lds[r * 257 + node];
      float br = ((t >> (7 - d)) & 1) ? (1.f - p) : p;
      P *= fmaxf(br, 1e-5f);
    }
    P_lds[r * 257 + t] = P;
  }
  if (t == 0) atomicAdd(reg_out, red[0] + red[1] + red[2] + red[3]);
  __syncthreads();

  // ---------------- Phase 2c: out[16][64] = P @ value ----------------
  {
    int o = t & 63, w4 = t >> 6;  // rows w4*4 .. +3
    float a0 = 0.f, a1 = 0.f, a2 = 0.f, a3 = 0.f;
    const float* vp = value + o;
    const float* Pr = P_lds + (w4 * 4) * 257;
#pragma unroll 4
    for (int l = 0; l < LV; l++) {
      float vv = vp[l * O];
      a0 += Pr[l] * vv;
      a1 += Pr[257 + l] * vv;
      a2 += Pr[2 * 257 + l] * vv;
      a3 += Pr[3 * 257 + l] * vv;
    }
    out[(R0 + w4 * 4 + 0) * O + o] = a0;
    out[(R0 + w4 * 4 + 1) * O + o] = a1;
    out[(R0 + w4 * 4 + 2) * O + o] = a2;
    out[(R0 + w4 * 4 + 3) * O + o] = a3;
  }
}

extern "C" void kernel_launch(void* const* d_in, const int* in_sizes, int n_in,
                              void* d_out, int out_size, void* d_ws, size_t ws_size,
                              hipStream_t stream) {
  const float* x     = (const float*)d_in[0];
  const float* Ws    = (const float*)d_in[1];
  const float* bs    = (const float*)d_in[2];
  const float* value = (const float*)d_in[3];
  float* out = (float*)d_out;
  float* reg_out = out + (size_t)Bsz * O;  // scalar reg slot at index 524288

  hipMemsetAsync(reg_out, 0, sizeof(float), stream);
  sdt_fused<<<Bsz / B_ROWS, 256, 0, stream>>>(x, Ws, bs, value, out, reg_out);
}

// Round 2
// 144.522 us; speedup vs baseline: 1.0962x; 1.0962x over previous
//
#include <hip/hip_runtime.h>

// SDT forward, fused. Identities:
//   out[b,o] = sum_l P[b,l] * v[l,o],  P[b,l] = prod_d max(branch_p, 1e-5)
//   reg = sum_{b,node} (-0.5 * 2^-depth / 8192) * log(max(p(1-p), 1e-5))
// GEMM: conflict-free LDS (lane-contiguous float4), 4x8 micro-tile,
// Ws pre-padded to [512][256] in d_ws by a tiny pre-kernel.

constexpr int Bsz = 8192, D = 512, NN = 255, LV = 256, O = 64;
constexpr int B_ROWS = 16, KC = 32, NT = 128;
constexpr int LSTR = 260;  // phase-2 row stride (mult of 4 for b128 align)

__global__ void pad_ws(const float* __restrict__ Ws, float* __restrict__ wsp) {
  int e = blockIdx.x * 256 + threadIdx.x;   // 131072 total
  int k = e >> 8, c = e & 255;
  wsp[e] = (c < NN) ? Ws[k * NN + c] : 0.f;
}

__global__ __launch_bounds__(NT, 2) void sdt_fused(
    const float* __restrict__ x, const float* __restrict__ wsp,
    const float* __restrict__ bs, const float* __restrict__ value,
    float* __restrict__ out, float* __restrict__ reg_out)
{
  __shared__ float smem[KC * 256 + KC * 20];   // 8832 floats = 35.3 KB
  float* Ws_lds = smem;                 // [KC][256]
  float* xT     = smem + KC * 256;      // [KC][20] (16 rows + pad)
  float* L_lds  = smem;                 // [16][260] logits -> p in place
  float* P_lds  = smem + 16 * LSTR;     // [16][260]
  float* red    = smem + 32 * LSTR;     // [2]

  const int t  = threadIdx.x;
  const int cg = t & 31;          // col quads: cg*4 and 128+cg*4
  const int rg = t >> 5;          // rows rg*4 .. rg*4+3
  const int R0 = blockIdx.x * B_ROWS;

  float acc[4][8];
#pragma unroll
  for (int r = 0; r < 4; r++)
#pragma unroll
    for (int j = 0; j < 8; j++) acc[r][j] = 0.f;

  // ---------------- Phase 1: logits = x @ Ws ----------------
  for (int k0 = 0; k0 < D; k0 += KC) {
    __syncthreads();
    // stage Ws chunk: [KC][256] straight copy, aligned float4 both sides
    {
      const float4* wsrc = (const float4*)(wsp + (size_t)k0 * 256);
      float4* wdst = (float4*)Ws_lds;
#pragma unroll
      for (int i = 0; i < (KC * 256 / 4) / NT; i++)   // 16 iters
        wdst[t + i * NT] = wsrc[t + i * NT];
    }
    // stage x chunk transposed: xT[kk][row]
    {
      int r = t >> 3, q = t & 7;
      float4 xv = *(const float4*)(x + (size_t)(R0 + r) * D + k0 + q * 4);
      xT[(q * 4 + 0) * 20 + r] = xv.x;
      xT[(q * 4 + 1) * 20 + r] = xv.y;
      xT[(q * 4 + 2) * 20 + r] = xv.z;
      xT[(q * 4 + 3) * 20 + r] = xv.w;
    }
    __syncthreads();
#pragma unroll 8
    for (int kk = 0; kk < KC; kk++) {
      float4 xv = *(const float4*)&xT[kk * 20 + rg * 4];
      float4 wa = *(const float4*)&Ws_lds[kk * 256 + cg * 4];
      float4 wb = *(const float4*)&Ws_lds[kk * 256 + 128 + cg * 4];
      float xr[4] = {xv.x, xv.y, xv.z, xv.w};
#pragma unroll
      for (int r = 0; r < 4; r++) {
        acc[r][0] += xr[r] * wa.x; acc[r][1] += xr[r] * wa.y;
        acc[r][2] += xr[r] * wa.z; acc[r][3] += xr[r] * wa.w;
        acc[r][4] += xr[r] * wb.x; acc[r][5] += xr[r] * wb.y;
        acc[r][6] += xr[r] * wb.z; acc[r][7] += xr[r] * wb.w;
      }
    }
  }
  __syncthreads();   // all Ws_lds reads done before L overwrite

  // write logits (+bias) to L_lds[16][260]
  {
    float ba[4], bb[4];
#pragma unroll
    for (int j = 0; j < 4; j++) {
      ba[j] = bs[cg * 4 + j];                       // < 128, always valid
      int cb = 128 + cg * 4 + j;
      bb[j] = (cb < NN) ? bs[cb] : 0.f;
    }
#pragma unroll
    for (int r = 0; r < 4; r++) {
      int row = rg * 4 + r;
      float4 la = {acc[r][0] + ba[0], acc[r][1] + ba[1],
                   acc[r][2] + ba[2], acc[r][3] + ba[3]};
      float4 lb = {acc[r][4] + bb[0], acc[r][5] + bb[1],
                   acc[r][6] + bb[2], acc[r][7] + bb[3]};
      *(float4*)&L_lds[row * LSTR + cg * 4] = la;
      *(float4*)&L_lds[row * LSTR + 128 + cg * 4] = lb;
    }
  }
  __syncthreads();

  // ------------- Phase 2a: p = sigmoid, reg partials -------------
  float regsum = 0.f;
  {
    // col A = t (0..127), col B = t+128 (guard < 255)
#pragma unroll
    for (int h = 0; h < 2; h++) {
      int col = t + h * 128;
      if (col < NN) {
        float s = 0.f;
        for (int r = 0; r < B_ROWS; r++) {
          float Lv = L_lds[r * LSTR + col];
          float p = 1.f / (1.f + __expf(-Lv));
          L_lds[r * LSTR + col] = p;     // exclusive owner of this col
          s += __logf(fmaxf(p * (1.f - p), 1e-5f));
        }
        int d = 31 - __clz(col + 1);
        regsum += s * (-0.5f / (8192.0f * (float)(1 << d)));
      }
    }
  }
#pragma unroll
  for (int off = 32; off; off >>= 1) regsum += __shfl_down(regsum, off, 64);
  if ((t & 63) == 0) red[t >> 6] = regsum;
  __syncthreads();   // p visible + red visible

  // ------------- Phase 2b: path products -------------
  if (t == 0) atomicAdd(reg_out, red[0] + red[1]);
  for (int r = 0; r < B_ROWS; r++) {
    const float* Lr = L_lds + r * LSTR;
#pragma unroll
    for (int h = 0; h < 2; h++) {
      int leaf = t + h * 128;
      float P = 1.f;
#pragma unroll
      for (int d = 0; d < 8; d++) {
        int node = (1 << d) - 1 + (leaf >> (8 - d));
        float p = Lr[node];
        float br = ((leaf >> (7 - d)) & 1) ? (1.f - p) : p;
        P *= fmaxf(br, 1e-5f);
      }
      P_lds[r * LSTR + leaf] = P;
    }
  }
  __syncthreads();

  // ------------- Phase 2c: out[16][64] = P @ value -------------
  {
    int o = t & 63, g = t >> 6;       // rows g*8 .. g*8+7
    float a[8];
#pragma unroll
    for (int r = 0; r < 8; r++) a[r] = 0.f;
    const float* Pb = P_lds + (g * 8) * LSTR;
    for (int l4 = 0; l4 < LV / 4; l4++) {
      float v0 = value[(l4 * 4 + 0) * O + o];
      float v1 = value[(l4 * 4 + 1) * O + o];
      float v2 = value[(l4 * 4 + 2) * O + o];
      float v3 = value[(l4 * 4 + 3) * O + o];
#pragma unroll
      for (int r = 0; r < 8; r++) {
        float4 p4 = *(const float4*)&Pb[r * LSTR + l4 * 4];
        a[r] += p4.x * v0 + p4.y * v1 + p4.z * v2 + p4.w * v3;
      }
    }
#pragma unroll
    for (int r = 0; r < 8; r++)
      out[(size_t)(R0 + g * 8 + r) * O + o] = a[r];
  }
}

extern "C" void kernel_launch(void* const* d_in, const int* in_sizes, int n_in,
                              void* d_out, int out_size, void* d_ws, size_t ws_size,
                              hipStream_t stream) {
  const float* x     = (const float*)d_in[0];
  const float* Ws    = (const float*)d_in[1];
  const float* bs    = (const float*)d_in[2];
  const float* value = (const float*)d_in[3];
  float* outp = (float*)d_out;
  float* reg_slot = outp + (size_t)Bsz * O;   // index 524288
  float* wsp = (float*)d_ws;                  // needs 512*256*4 = 512 KB

  hipMemsetAsync(reg_slot, 0, sizeof(float), stream);
  pad_ws<<<512, 256, 0, stream>>>(Ws, wsp);
  sdt_fused<<<Bsz / B_ROWS, NT, 0, stream>>>(x, wsp, bs, value, outp, reg_slot);
}

// Round 3
// 100.129 us; speedup vs baseline: 1.5822x; 1.4434x over previous
//
#include <hip/hip_runtime.h>

// SDT forward, bf16 split-precision MFMA.
//   logits = x @ W  computed as  xh@wh + xh@wl + xl@wh  (bf16 hi/lo, fp32 acc)
//   out[b,o] = sum_l P[b,l] * value[l,o],  P = prod_d max(branch_p, 1e-5)
//   reg = sum_{b,node} (-0.5 * 2^-depth / 8192) * log(max(p(1-p), 1e-5))
// MFMA 16x16x32_bf16; A/B^T row-major frags (lane&15 -> row, (lane>>4)*8 -> k),
// C/D: col=lane&15, row=(lane>>4)*4+reg  (HW-verified layouts).

typedef __attribute__((ext_vector_type(8))) short short8;
typedef __attribute__((ext_vector_type(4))) float floatx4;

constexpr int D = 512, NN = 255, O = 64, M_BLK = 32;
constexpr int XPAD = 40;   // x LDS row stride in bf16 (80 B -> <=2-way banks)

__device__ __forceinline__ short f2bf(float f) {
  unsigned u = __builtin_bit_cast(unsigned, f);
  u += 0x7fffu + ((u >> 16) & 1u);          // RNE
  return (short)(u >> 16);
}
__device__ __forceinline__ float bf2f(short h) {
  unsigned u = ((unsigned)(unsigned short)h) << 16;
  return __builtin_bit_cast(float, u);
}
__device__ __forceinline__ int pk2(short a, short b) {
  return (int)((unsigned short)a | ((unsigned)(unsigned short)b << 16));
}

// ---- pre-kernel: transpose + hi/lo split W, zero reg slot ----
__global__ void sdt_pre(const float* __restrict__ Ws, short* __restrict__ wth,
                        short* __restrict__ wtl, float* __restrict__ reg_slot) {
  int k = blockIdx.x;      // 0..511
  int n = threadIdx.x;     // 0..255
  float f = (n < NN) ? Ws[k * NN + n] : 0.f;
  short h = f2bf(f);
  short l = f2bf(f - bf2f(h));
  wth[n * D + k] = h;
  wtl[n * D + k] = l;
  if (k == 0 && n == 0) *reg_slot = 0.f;
}

__global__ __launch_bounds__(512, 2) void sdt_main(
    const float* __restrict__ x, const short* __restrict__ wth,
    const short* __restrict__ wtl, const float* __restrict__ bs,
    const float* __restrict__ value, float* __restrict__ out,
    float* __restrict__ reg_out)
{
  __shared__ short xh_s[M_BLK * XPAD];
  __shared__ short xl_s[M_BLK * XPAD];
  __shared__ float L_s[M_BLK * 260];
  __shared__ float P_s[M_BLK * 260];
  __shared__ float red_s[8];

  const int t = threadIdx.x;
  const int lane = t & 63, w = t >> 6;        // 8 waves
  const int q = lane >> 4, r16 = lane & 15;
  const int R0 = blockIdx.x * M_BLK;

  // B-frag element offsets (shorts): row n, k-offset q*8 (chunk adds c*32)
  const int nb0 = (w * 32 + r16) * D + q * 8;        // nt = 2w
  const int nb1 = (w * 32 + 16 + r16) * D + q * 8;   // nt = 2w+1
  // A-frag LDS offsets (shorts)
  const int aoff0 = (r16) * XPAD + q * 8;            // mt = 0
  const int aoff1 = (16 + r16) * XPAD + q * 8;       // mt = 1
  // x staging map (threads 0..255): row t>>3, quad t&7
  const int xr = t >> 3, xq = t & 7;
  const float* xg = x + (size_t)(R0 + xr) * D + xq * 4;

  floatx4 acc00 = {0,0,0,0}, acc01 = {0,0,0,0}, acc10 = {0,0,0,0}, acc11 = {0,0,0,0};
  short8 bh[3][2], bl[3][2];
  float4 xf[3];
  int xph0 = 0, xph1 = 0, xpl0 = 0, xpl1 = 0;   // packed bf16 quads for next chunk

  // -------- prologue: W chunks 0,1 ; x chunks 0,1,2 --------
#pragma unroll
  for (int s = 0; s < 2; ++s) {
    bh[s][0] = *(const short8*)(wth + nb0 + s * 32);
    bl[s][0] = *(const short8*)(wtl + nb0 + s * 32);
    bh[s][1] = *(const short8*)(wth + nb1 + s * 32);
    bl[s][1] = *(const short8*)(wtl + nb1 + s * 32);
  }
  if (t < 256) {
    xf[0] = *(const float4*)(xg + 0 * 32);
    xf[1] = *(const float4*)(xg + 1 * 32);
    xf[2] = *(const float4*)(xg + 2 * 32);
    // convert + store chunk 0
    short h0 = f2bf(xf[0].x), h1 = f2bf(xf[0].y), h2 = f2bf(xf[0].z), h3 = f2bf(xf[0].w);
    short l0 = f2bf(xf[0].x - bf2f(h0)), l1 = f2bf(xf[0].y - bf2f(h1));
    short l2 = f2bf(xf[0].z - bf2f(h2)), l3 = f2bf(xf[0].w - bf2f(h3));
    *(int*)&xh_s[xr * XPAD + xq * 4]     = pk2(h0, h1);
    *(int*)&xh_s[xr * XPAD + xq * 4 + 2] = pk2(h2, h3);
    *(int*)&xl_s[xr * XPAD + xq * 4]     = pk2(l0, l1);
    *(int*)&xl_s[xr * XPAD + xq * 4 + 2] = pk2(l2, l3);
  }
  __syncthreads();

  // -------- main K loop: 16 chunks of 32 --------
#pragma unroll
  for (int c = 0; c < 16; ++c) {
    const int s0 = c % 3, s1 = (c + 1) % 3, s2 = (c + 2) % 3, s3 = (c + 3) % 3;
    if (c + 2 < 16) {
      bh[s2][0] = *(const short8*)(wth + nb0 + (c + 2) * 32);
      bl[s2][0] = *(const short8*)(wtl + nb0 + (c + 2) * 32);
      bh[s2][1] = *(const short8*)(wth + nb1 + (c + 2) * 32);
      bl[s2][1] = *(const short8*)(wtl + nb1 + (c + 2) * 32);
    }
    if (c + 3 < 16 && t < 256) xf[s3] = *(const float4*)(xg + (c + 3) * 32);

    short8 ah0 = *(const short8*)&xh_s[aoff0];
    short8 al0 = *(const short8*)&xl_s[aoff0];
    short8 ah1 = *(const short8*)&xh_s[aoff1];
    short8 al1 = *(const short8*)&xl_s[aoff1];

    acc00 = __builtin_amdgcn_mfma_f32_16x16x32_bf16(ah0, bh[s0][0], acc00, 0, 0, 0);
    acc01 = __builtin_amdgcn_mfma_f32_16x16x32_bf16(ah0, bh[s0][1], acc01, 0, 0, 0);
    acc10 = __builtin_amdgcn_mfma_f32_16x16x32_bf16(ah1, bh[s0][0], acc10, 0, 0, 0);
    acc11 = __builtin_amdgcn_mfma_f32_16x16x32_bf16(ah1, bh[s0][1], acc11, 0, 0, 0);
    acc00 = __builtin_amdgcn_mfma_f32_16x16x32_bf16(ah0, bl[s0][0], acc00, 0, 0, 0);
    acc01 = __builtin_amdgcn_mfma_f32_16x16x32_bf16(ah0, bl[s0][1], acc01, 0, 0, 0);
    acc10 = __builtin_amdgcn_mfma_f32_16x16x32_bf16(ah1, bl[s0][0], acc10, 0, 0, 0);
    acc11 = __builtin_amdgcn_mfma_f32_16x16x32_bf16(ah1, bl[s0][1], acc11, 0, 0, 0);
    acc00 = __builtin_amdgcn_mfma_f32_16x16x32_bf16(al0, bh[s0][0], acc00, 0, 0, 0);
    acc01 = __builtin_amdgcn_mfma_f32_16x16x32_bf16(al0, bh[s0][1], acc01, 0, 0, 0);
    acc10 = __builtin_amdgcn_mfma_f32_16x16x32_bf16(al1, bh[s0][0], acc10, 0, 0, 0);
    acc11 = __builtin_amdgcn_mfma_f32_16x16x32_bf16(al1, bh[s0][1], acc11, 0, 0, 0);

    if (c + 1 < 16 && t < 256) {
      float4 xv = xf[s1];
      short h0 = f2bf(xv.x), h1 = f2bf(xv.y), h2 = f2bf(xv.z), h3 = f2bf(xv.w);
      short l0 = f2bf(xv.x - bf2f(h0)), l1 = f2bf(xv.y - bf2f(h1));
      short l2 = f2bf(xv.z - bf2f(h2)), l3 = f2bf(xv.w - bf2f(h3));
      xph0 = pk2(h0, h1); xph1 = pk2(h2, h3);
      xpl0 = pk2(l0, l1); xpl1 = pk2(l2, l3);
    }
    __syncthreads();                 // all A-frag reads of x buffer done
    if (c + 1 < 16 && t < 256) {
      *(int*)&xh_s[xr * XPAD + xq * 4]     = xph0;
      *(int*)&xh_s[xr * XPAD + xq * 4 + 2] = xph1;
      *(int*)&xl_s[xr * XPAD + xq * 4]     = xpl0;
      *(int*)&xl_s[xr * XPAD + xq * 4 + 2] = xpl1;
    }
    __syncthreads();                 // next x chunk visible
  }

  // -------- epilogue: C frags -> L_s --------
  {
    // wave w: cols w*32 + j*16 + r16 ; rows mt*16 + q*4 + reg
#pragma unroll
    for (int r = 0; r < 4; ++r) {
      int row0 = q * 4 + r, row1 = 16 + q * 4 + r;
      int c0 = w * 32 + r16, c1 = w * 32 + 16 + r16;
      L_s[row0 * 260 + c0] = acc00[r];
      L_s[row0 * 260 + c1] = acc01[r];
      L_s[row1 * 260 + c0] = acc10[r];
      L_s[row1 * 260 + c1] = acc11[r];
    }
  }
  __syncthreads();

  // -------- phase 2a: sigmoid (+bias), reg partial --------
  const int col = t & 255, half = t >> 8;
  float rsum = 0.f;
  if (col < NN) {
    float b = bs[col];
    for (int r = half * 16; r < half * 16 + 16; ++r) {
      float z = L_s[r * 260 + col] + b;
      float p = 1.f / (1.f + __expf(-z));
      L_s[r * 260 + col] = p;               // exclusive (col, row-half) owner
      rsum += __logf(fmaxf(p * (1.f - p), 1e-5f));
    }
    int dd = 31 - __clz(col + 1);
    rsum *= -0.5f / (8192.0f * (float)(1 << dd));
  }
#pragma unroll
  for (int off = 32; off; off >>= 1) rsum += __shfl_down(rsum, off, 64);
  if (lane == 0) red_s[w] = rsum;
  __syncthreads();
  if (t == 0) {
    float s = 0.f;
#pragma unroll
    for (int i = 0; i < 8; ++i) s += red_s[i];
    atomicAdd(reg_out, s);
  }

  // -------- phase 2b: path products --------
  {
    const int leaf = col;
    for (int r = half * 16; r < half * 16 + 16; ++r) {
      const float* Lr = &L_s[r * 260];
      float P = 1.f;
#pragma unroll
      for (int dd = 0; dd < 8; ++dd) {
        int node = (1 << dd) - 1 + (leaf >> (8 - dd));
        float p = Lr[node];
        float br = ((leaf >> (7 - dd)) & 1) ? (1.f - p) : p;
        P *= fmaxf(br, 1e-5f);
      }
      P_s[r * 260 + leaf] = P;
    }
  }
  __syncthreads();

  // -------- phase 2c: out[32][64] = P @ value --------
  {
    const int o = t & 63, g = t >> 6;     // 4 rows per wave
    float a0 = 0.f, a1 = 0.f, a2 = 0.f, a3 = 0.f;
    const float* Pb = &P_s[(g * 4) * 260];
    for (int l4 = 0; l4 < 64; ++l4) {
      float v0 = value[(l4 * 4 + 0) * O + o];
      float v1 = value[(l4 * 4 + 1) * O + o];
      float v2 = value[(l4 * 4 + 2) * O + o];
      float v3 = value[(l4 * 4 + 3) * O + o];
      float4 p0 = *(const float4*)&Pb[0 * 260 + l4 * 4];
      float4 p1 = *(const float4*)&Pb[1 * 260 + l4 * 4];
      float4 p2 = *(const float4*)&Pb[2 * 260 + l4 * 4];
      float4 p3 = *(const float4*)&Pb[3 * 260 + l4 * 4];
      a0 += p0.x * v0 + p0.y * v1 + p0.z * v2 + p0.w * v3;
      a1 += p1.x * v0 + p1.y * v1 + p1.z * v2 + p1.w * v3;
      a2 += p2.x * v0 + p2.y * v1 + p2.z * v2 + p2.w * v3;
      a3 += p3.x * v0 + p3.y * v1 + p3.z * v2 + p3.w * v3;
    }
    out[(size_t)(R0 + g * 4 + 0) * O + o] = a0;
    out[(size_t)(R0 + g * 4 + 1) * O + o] = a1;
    out[(size_t)(R0 + g * 4 + 2) * O + o] = a2;
    out[(size_t)(R0 + g * 4 + 3) * O + o] = a3;
  }
}

extern "C" void kernel_launch(void* const* d_in, const int* in_sizes, int n_in,
                              void* d_out, int out_size, void* d_ws, size_t ws_size,
                              hipStream_t stream) {
  const float* x     = (const float*)d_in[0];
  const float* Ws    = (const float*)d_in[1];
  const float* bs    = (const float*)d_in[2];
  const float* value = (const float*)d_in[3];
  float* outp = (float*)d_out;
  float* reg_slot = outp + (size_t)8192 * O;       // index 524288
  short* wth = (short*)d_ws;                       // [256][512] bf16
  short* wtl = wth + 256 * 512;                    // [256][512] bf16

  sdt_pre<<<512, 256, 0, stream>>>(Ws, wth, wtl, reg_slot);
  sdt_main<<<8192 / M_BLK, 512, 0, stream>>>(x, wth, wtl, bs, value, outp, reg_slot);
}